// Round 2
// baseline (450.816 us; speedup 1.0000x reference)
//
#include <hip/hip_runtime.h>

// GCN 2-layer + edge dot decoder. Dims fixed: in=512, hid=128, out=64.
#define IN_C  512
#define HID_C 128
#define OUT_C 64

using short8 = __attribute__((ext_vector_type(8))) short;   // 8 bf16
using floatx4 = __attribute__((ext_vector_type(4))) float;  // mfma acc
using floatx8 = __attribute__((ext_vector_type(8))) float;  // 32B A-frag load

__device__ inline unsigned short f2bf(float f) {  // RNE
    unsigned u = __builtin_bit_cast(unsigned, f);
    u += 0x7FFFu + ((u >> 16) & 1u);
    return (unsigned short)(u >> 16);
}
__device__ inline float bf2f(unsigned short h) {
    unsigned u = ((unsigned)h) << 16;
    return __builtin_bit_cast(float, u);
}

// ---------------- CSR build ----------------
__global__ void k_zero_int(int* __restrict__ p, int n) {
    int i = blockIdx.x * blockDim.x + threadIdx.x;
    if (i < n) p[i] = 0;
}

__global__ void k_count(const int* __restrict__ dst, int* __restrict__ cnt, int e) {
    int i = blockIdx.x * blockDim.x + threadIdx.x;
    if (i < e) atomicAdd(&cnt[dst[i]], 1);
}

__global__ void k_dinv(const int* __restrict__ cnt, float* __restrict__ dinv, int n) {
    int i = blockIdx.x * blockDim.x + threadIdx.x;
    if (i < n) dinv[i] = rsqrtf(1.0f + (float)cnt[i]);  // +1 self-loop
}

__global__ void k_blocksum(const int* __restrict__ cnt, int* __restrict__ bsum, int n) {
    __shared__ int sdata[256];
    int t = threadIdx.x;
    int i = blockIdx.x * 256 + t;
    sdata[t] = (i < n) ? cnt[i] : 0;
    __syncthreads();
    for (int s = 128; s > 0; s >>= 1) {
        if (t < s) sdata[t] += sdata[t + s];
        __syncthreads();
    }
    if (t == 0) bsum[blockIdx.x] = sdata[0];
}

__global__ void k_scanpartials(int* __restrict__ bsum, int nb) {
    __shared__ int sdata[256];
    int t = threadIdx.x;
    int orig = (t < nb) ? bsum[t] : 0;
    sdata[t] = orig;
    __syncthreads();
    for (int off = 1; off < 256; off <<= 1) {
        int v = (t >= off) ? sdata[t - off] : 0;
        __syncthreads();
        sdata[t] += v;
        __syncthreads();
    }
    if (t < nb) bsum[t] = sdata[t] - orig;  // exclusive
}

__global__ void k_scanfinal(const int* __restrict__ cnt, const int* __restrict__ bsum_ex,
                            int* __restrict__ row_ptr, int n, int e_total) {
    __shared__ int sdata[256];
    int t = threadIdx.x;
    int i = blockIdx.x * 256 + t;
    int orig = (i < n) ? cnt[i] : 0;
    sdata[t] = orig;
    __syncthreads();
    for (int off = 1; off < 256; off <<= 1) {
        int v = (t >= off) ? sdata[t - off] : 0;
        __syncthreads();
        sdata[t] += v;
        __syncthreads();
    }
    if (i < n) row_ptr[i] = sdata[t] - orig + bsum_ex[blockIdx.x];
    if (i == 0) row_ptr[n] = e_total;
}

__global__ void k_fill(const int* __restrict__ src, const int* __restrict__ dst,
                       const int* __restrict__ row_ptr, int* __restrict__ cur,
                       int* __restrict__ col, int e) {
    int i = blockIdx.x * blockDim.x + threadIdx.x;
    if (i < e) {
        int d = dst[i];
        int pos = atomicAdd(&cur[d], 1);
        col[row_ptr[d] + pos] = src[i];
    }
}

// ---------------- weight prep: W [K][N] fp32 -> Wt_hi/Wt_lo [N][K] bf16 ----------------
__global__ void k_prep_w(const float* __restrict__ W, unsigned short* __restrict__ hi,
                         unsigned short* __restrict__ lo, int K, int N) {
    int i = blockIdx.x * blockDim.x + threadIdx.x;
    if (i >= K * N) return;
    int k = i / N, n = i % N;
    float v = W[i];
    unsigned short h = f2bf(v);
    float r = v - bf2f(h);
    hi[(long)n * K + k] = h;
    lo[(long)n * K + k] = f2bf(r);
}

// ---------------- direct-from-global split-bf16 MFMA GEMM ----------------
// No LDS, no barriers: the MFMA A-fragment is loaded straight from global memory.
// Lane l reads 8 consecutive fp32 at A[row = base + (l&15)][k = t*32 + (l>>4)*8]
// (32 B/lane; each 128 B row-segment is fully consumed by 4 lanes -> 100% line use),
// converts to split-bf16 (hi + lo) in-register, and issues 3 MFMAs per (mi,ni).
// B (weights, hi+lo bf16, [N][K]) is tiny and L2-resident; loaded per wave per tile.
// Waves are fully independent -> latency hidden by ILP (depth-2 A prefetch,
// statically indexed: t-loop is fully unrolled so pf[t&1] never hits scratch).
// K-summation order (ascending 32-chunks; hh,hl,lh per chunk) is identical to the
// previous LDS kernel -> bitwise-identical numerics.
template <int K, int MI, int NPW, int WM, int WN>
__global__ __launch_bounds__(256) void k_gemm_direct(
    const float* __restrict__ A, const unsigned short* __restrict__ Bt_hi,
    const unsigned short* __restrict__ Bt_lo, const float* __restrict__ dinv,
    float* __restrict__ Hs, int M) {
    constexpr int N = WN * NPW * 16;   // output width
    constexpr int BM = WM * MI * 16;   // rows per block
    constexpr int NT = K / 32;         // k-steps (one 16x16x32 MFMA chunk each)

    const int tid = threadIdx.x;
    const int w = tid >> 6;
    const int lane = tid & 63;
    const int wm = w / WN;
    const int wn = w % WN;
    const int m = lane & 15;
    const int quad = lane >> 4;
    const int rowbase = blockIdx.x * BM + wm * (MI * 16);
    const int colbase = wn * (NPW * 16);
    const int koff = quad * 8;

    // per-lane A offsets (row clamped: rows >= M compute garbage, never stored;
    // MFMA output rows depend only on the same A row -> no cross-contamination)
    long aoff[MI];
#pragma unroll
    for (int mi = 0; mi < MI; ++mi) {
        int r = rowbase + mi * 16 + m;
        if (r > M - 1) r = M - 1;
        aoff[mi] = (long)r * K + koff;
    }
    long boff[NPW];
#pragma unroll
    for (int ni = 0; ni < NPW; ++ni)
        boff[ni] = (long)(colbase + ni * 16 + m) * K + koff;

    floatx4 acc[MI][NPW];
#pragma unroll
    for (int mi = 0; mi < MI; ++mi)
#pragma unroll
        for (int ni = 0; ni < NPW; ++ni) acc[mi][ni] = (floatx4){0.f, 0.f, 0.f, 0.f};

    // depth-2 A prefetch pipeline
    floatx8 pf[2][MI];
#pragma unroll
    for (int mi = 0; mi < MI; ++mi) pf[0][mi] = *(const floatx8*)&A[aoff[mi]];
    if (NT > 1) {
#pragma unroll
        for (int mi = 0; mi < MI; ++mi) pf[1][mi] = *(const floatx8*)&A[aoff[mi] + 32];
    }

#pragma unroll
    for (int t = 0; t < NT; ++t) {
        // convert current A frag to split-bf16
        short8 ah[MI], al[MI];
#pragma unroll
        for (int mi = 0; mi < MI; ++mi) {
            floatx8 v = pf[t & 1][mi];
#pragma unroll
            for (int j = 0; j < 8; ++j) {
                unsigned short h = f2bf(v[j]);
                ah[mi][j] = (short)h;
                al[mi][j] = (short)f2bf(v[j] - bf2f(h));
            }
        }
        // refill this slot with tile t+2 (overlaps with MFMAs below)
        if (t + 2 < NT) {
#pragma unroll
            for (int mi = 0; mi < MI; ++mi)
                pf[t & 1][mi] = *(const floatx8*)&A[aoff[mi] + (t + 2) * 32];
        }
#pragma unroll
        for (int ni = 0; ni < NPW; ++ni) {
            short8 bh = *(const short8*)&Bt_hi[boff[ni] + t * 32];
            short8 bl = *(const short8*)&Bt_lo[boff[ni] + t * 32];
#pragma unroll
            for (int mi = 0; mi < MI; ++mi) {
                acc[mi][ni] = __builtin_amdgcn_mfma_f32_16x16x32_bf16(ah[mi], bh, acc[mi][ni], 0, 0, 0);
                acc[mi][ni] = __builtin_amdgcn_mfma_f32_16x16x32_bf16(ah[mi], bl, acc[mi][ni], 0, 0, 0);
                acc[mi][ni] = __builtin_amdgcn_mfma_f32_16x16x32_bf16(al[mi], bh, acc[mi][ni], 0, 0, 0);
            }
        }
    }

    // epilogue: C/D layout col=lane&15, row=quad*4+reg; scale by dinv[row]
#pragma unroll
    for (int mi = 0; mi < MI; ++mi) {
#pragma unroll
        for (int r = 0; r < 4; ++r) {
            int row = rowbase + mi * 16 + quad * 4 + r;
            if (row < M) {
                float dv = dinv[row];
#pragma unroll
                for (int ni = 0; ni < NPW; ++ni) {
                    int n = colbase + ni * 16 + m;
                    Hs[(long)row * N + n] = acc[mi][ni][r] * dv;
                }
            }
        }
    }
}

// ---------------- CSR aggregation, wave per node, 4x unrolled gathers ----------------
__global__ __launch_bounds__(256) void k_agg1(
    const float* __restrict__ h, const int* __restrict__ row_ptr,
    const int* __restrict__ col, const float* __restrict__ dinv,
    const float* __restrict__ bias, float* __restrict__ z, int n) {
    int node = blockIdx.x * 4 + (threadIdx.x >> 6);
    node = __builtin_amdgcn_readfirstlane(node);
    if (node >= n) return;
    int lane = threadIdx.x & 63;
    const float2* hp = (const float2*)h;
    float2 acc = hp[(long)node * 64 + lane];  // self-loop
    int rs = row_ptr[node], re = row_ptr[node + 1];
    int j = rs;
    for (; j + 4 <= re; j += 4) {
        int s0 = col[j], s1 = col[j + 1], s2 = col[j + 2], s3 = col[j + 3];
        float2 v0 = hp[(long)s0 * 64 + lane];
        float2 v1 = hp[(long)s1 * 64 + lane];
        float2 v2 = hp[(long)s2 * 64 + lane];
        float2 v3 = hp[(long)s3 * 64 + lane];
        acc.x += v0.x + v1.x + v2.x + v3.x;
        acc.y += v0.y + v1.y + v2.y + v3.y;
    }
    for (; j < re; ++j) {
        int s = col[j];
        float2 v = hp[(long)s * 64 + lane];
        acc.x += v.x;
        acc.y += v.y;
    }
    float dv = dinv[node];
    float2 b = ((const float2*)bias)[lane];
    acc.x = fmaxf(fmaf(acc.x, dv, b.x), 0.f);
    acc.y = fmaxf(fmaf(acc.y, dv, b.y), 0.f);
    ((float2*)z)[(long)node * 64 + lane] = acc;
}

__global__ __launch_bounds__(256) void k_agg2(
    const float* __restrict__ h, const int* __restrict__ row_ptr,
    const int* __restrict__ col, const float* __restrict__ dinv,
    const float* __restrict__ bias, float* __restrict__ z, int n) {
    int node = blockIdx.x * 4 + (threadIdx.x >> 6);
    node = __builtin_amdgcn_readfirstlane(node);
    if (node >= n) return;
    int lane = threadIdx.x & 63;
    float acc = h[(long)node * 64 + lane];  // self-loop
    int rs = row_ptr[node], re = row_ptr[node + 1];
    int j = rs;
    for (; j + 4 <= re; j += 4) {
        int s0 = col[j], s1 = col[j + 1], s2 = col[j + 2], s3 = col[j + 3];
        acc += h[(long)s0 * 64 + lane] + h[(long)s1 * 64 + lane] +
               h[(long)s2 * 64 + lane] + h[(long)s3 * 64 + lane];
    }
    for (; j < re; ++j) acc += h[(long)col[j] * 64 + lane];
    z[(long)node * 64 + lane] = fmaf(acc, dinv[node], bias[lane]);
}

// ---------------- decoder ----------------
__global__ void k_dot(const float* __restrict__ z2, const int* __restrict__ es,
                      const int* __restrict__ ed, float* __restrict__ out, int L) {
    int gid = blockIdx.x * blockDim.x + threadIdx.x;
    int wid = gid >> 6;
    int lane = threadIdx.x & 63;
    if (wid >= L) return;
    int a = es[wid], b = ed[wid];
    float v = z2[(long)a * OUT_C + lane] * z2[(long)b * OUT_C + lane];
#pragma unroll
    for (int off = 32; off > 0; off >>= 1) v += __shfl_down(v, off);
    if (lane == 0) out[wid] = v;
}

extern "C" void kernel_launch(void* const* d_in, const int* in_sizes, int n_in,
                              void* d_out, int out_size, void* d_ws, size_t ws_size,
                              hipStream_t stream) {
    const float* x = (const float*)d_in[0];
    const int* ei = (const int*)d_in[1];
    const int* eli = (const int*)d_in[2];
    const float* W1 = (const float*)d_in[3];
    const float* b1 = (const float*)d_in[4];
    const float* W2 = (const float*)d_in[5];
    const float* b2 = (const float*)d_in[6];
    float* out = (float*)d_out;

    const int N = in_sizes[0] / IN_C;  // 50000
    const int E = in_sizes[1] / 2;     // 800000
    const int L = in_sizes[2] / 2;     // 100000
    const int* src = ei;
    const int* dst = ei + E;
    const int* es = eli;
    const int* ed = eli + L;

    const int Npad = (N + 63) & ~63;
    const int Epad = (E + 3) & ~3;

    // workspace layout (~56 MB)
    int* cnt = (int*)d_ws;             // Npad
    int* cur = cnt + Npad;             // Npad
    int* row_ptr = cur + Npad;         // Npad + 64
    int* bsum = row_ptr + Npad + 64;   // 256
    int* col = bsum + 256;             // Epad
    float* dinv = (float*)(col + Epad);    // Npad
    float* h1s = dinv + Npad;              // N*128
    float* z1 = h1s + (long)N * HID_C;     // N*128
    float* h2s = h1s;                      // alias: h1s dead after agg1
    float* z2 = h1s + (long)N * OUT_C;     // alias: disjoint from h2s
    unsigned short* wt1_hi = (unsigned short*)(z1 + (long)N * HID_C);  // 512*128
    unsigned short* wt1_lo = wt1_hi + IN_C * HID_C;
    unsigned short* wt2_hi = wt1_lo + IN_C * HID_C;                    // 128*64
    unsigned short* wt2_lo = wt2_hi + HID_C * OUT_C;

    const int TPB = 256;
    const int nb = (N + 255) / 256;

    // weight prep
    k_prep_w<<<(IN_C * HID_C + TPB - 1) / TPB, TPB, 0, stream>>>(W1, wt1_hi, wt1_lo, IN_C, HID_C);
    k_prep_w<<<(HID_C * OUT_C + TPB - 1) / TPB, TPB, 0, stream>>>(W2, wt2_hi, wt2_lo, HID_C, OUT_C);

    // CSR build + dinv
    k_zero_int<<<(2 * Npad + TPB - 1) / TPB, TPB, 0, stream>>>(cnt, 2 * Npad);
    k_count<<<(E + TPB - 1) / TPB, TPB, 0, stream>>>(dst, cnt, E);
    k_dinv<<<(N + TPB - 1) / TPB, TPB, 0, stream>>>(cnt, dinv, N);
    k_blocksum<<<nb, 256, 0, stream>>>(cnt, bsum, N);
    k_scanpartials<<<1, 256, 0, stream>>>(bsum, nb);
    k_scanfinal<<<nb, 256, 0, stream>>>(cnt, bsum, row_ptr, N, E);
    k_fill<<<(E + TPB - 1) / TPB, TPB, 0, stream>>>(src, dst, row_ptr, cur, col, E);

    // layer 1: block = 4 waves (2M x 2N), wave = 32 rows x 64 cols; 64 rows/block
    k_gemm_direct<IN_C, 2, 4, 2, 2><<<(N + 63) / 64, 256, 0, stream>>>(x, wt1_hi, wt1_lo, dinv, h1s, N);
    k_agg1<<<(N + 3) / 4, 256, 0, stream>>>(h1s, row_ptr, col, dinv, b1, z1, N);

    // layer 2: block = 4 waves (4M x 1N), wave = 16 rows x 64 cols; 64 rows/block
    k_gemm_direct<HID_C, 1, 4, 4, 1><<<(N + 63) / 64, 256, 0, stream>>>(z1, wt2_hi, wt2_lo, dinv, h2s, N);
    k_agg2<<<(N + 3) / 4, 256, 0, stream>>>(h2s, row_ptr, col, dinv, b2, z2, N);

    // decoder
    k_dot<<<((long)L * 64 + TPB - 1) / TPB, TPB, 0, stream>>>(z2, es, ed, out, L);
}

// Round 3
// 413.063 us; speedup vs baseline: 1.0914x; 1.0914x over previous
//
#include <hip/hip_runtime.h>

// GCN 2-layer + edge dot decoder. Dims fixed: in=512, hid=128, out=64.
#define IN_C  512
#define HID_C 128
#define OUT_C 64

using short8 = __attribute__((ext_vector_type(8))) short;   // 8 bf16
using floatx4 = __attribute__((ext_vector_type(4))) float;  // mfma acc

__device__ inline unsigned short f2bf(float f) {  // RNE
    unsigned u = __builtin_bit_cast(unsigned, f);
    u += 0x7FFFu + ((u >> 16) & 1u);
    return (unsigned short)(u >> 16);
}
__device__ inline float bf2f(unsigned short h) {
    unsigned u = ((unsigned)h) << 16;
    return __builtin_bit_cast(float, u);
}

// ---------------- CSR build ----------------
__global__ void k_zero_int(int* __restrict__ p, int n) {
    int i = blockIdx.x * blockDim.x + threadIdx.x;
    if (i < n) p[i] = 0;
}

__global__ void k_count(const int* __restrict__ dst, int* __restrict__ cnt, int e) {
    int i = blockIdx.x * blockDim.x + threadIdx.x;
    if (i < e) atomicAdd(&cnt[dst[i]], 1);
}

__global__ void k_dinv(const int* __restrict__ cnt, float* __restrict__ dinv, int n) {
    int i = blockIdx.x * blockDim.x + threadIdx.x;
    if (i < n) dinv[i] = rsqrtf(1.0f + (float)cnt[i]);  // +1 self-loop
}

__global__ void k_blocksum(const int* __restrict__ cnt, int* __restrict__ bsum, int n) {
    __shared__ int sdata[256];
    int t = threadIdx.x;
    int i = blockIdx.x * 256 + t;
    sdata[t] = (i < n) ? cnt[i] : 0;
    __syncthreads();
    for (int s = 128; s > 0; s >>= 1) {
        if (t < s) sdata[t] += sdata[t + s];
        __syncthreads();
    }
    if (t == 0) bsum[blockIdx.x] = sdata[0];
}

__global__ void k_scanpartials(int* __restrict__ bsum, int nb) {
    __shared__ int sdata[256];
    int t = threadIdx.x;
    int orig = (t < nb) ? bsum[t] : 0;
    sdata[t] = orig;
    __syncthreads();
    for (int off = 1; off < 256; off <<= 1) {
        int v = (t >= off) ? sdata[t - off] : 0;
        __syncthreads();
        sdata[t] += v;
        __syncthreads();
    }
    if (t < nb) bsum[t] = sdata[t] - orig;  // exclusive
}

__global__ void k_scanfinal(const int* __restrict__ cnt, const int* __restrict__ bsum_ex,
                            int* __restrict__ row_ptr, int n, int e_total) {
    __shared__ int sdata[256];
    int t = threadIdx.x;
    int i = blockIdx.x * 256 + t;
    int orig = (i < n) ? cnt[i] : 0;
    sdata[t] = orig;
    __syncthreads();
    for (int off = 1; off < 256; off <<= 1) {
        int v = (t >= off) ? sdata[t - off] : 0;
        __syncthreads();
        sdata[t] += v;
        __syncthreads();
    }
    if (i < n) row_ptr[i] = sdata[t] - orig + bsum_ex[blockIdx.x];
    if (i == 0) row_ptr[n] = e_total;
}

__global__ void k_fill(const int* __restrict__ src, const int* __restrict__ dst,
                       const int* __restrict__ row_ptr, int* __restrict__ cur,
                       int* __restrict__ col, int e) {
    int i = blockIdx.x * blockDim.x + threadIdx.x;
    if (i < e) {
        int d = dst[i];
        int pos = atomicAdd(&cur[d], 1);
        col[row_ptr[d] + pos] = src[i];
    }
}

// ---------------- weight prep: W [K][N] fp32 -> Wt_hi/Wt_lo [N][K] bf16 ----------------
__global__ void k_prep_w(const float* __restrict__ W, unsigned short* __restrict__ hi,
                         unsigned short* __restrict__ lo, int K, int N) {
    int i = blockIdx.x * blockDim.x + threadIdx.x;
    if (i >= K * N) return;
    int k = i / N, n = i % N;
    float v = W[i];
    unsigned short h = f2bf(v);
    float r = v - bf2f(h);
    hi[(long)n * K + k] = h;
    lo[(long)n * K + k] = f2bf(r);
}

// ---------------- split-bf16 MFMA GEMM, depth-2 register prefetch, raw barrier ----------------
// Block 256 (4 waves), BM=64 rows, N = 64*NPW cols. LDS double-buffered A tiles.
// Depth-2 pipeline: loads for tile t+2 are issued at the top of tile t and converted
// at the end of tile t+1 (~2 tile-times of latency budget -> HBM latency covered).
// Raw s_barrier + explicit lgkmcnt(0) instead of __syncthreads: global prefetch loads
// stay in flight across barriers (no vmcnt(0) drain); compiler emits counted waits at
// the convert's use sites. Two named pf sets (pfA even tiles' t+2, pfB odd) keep all
// indexing static (no scratch).
// LDS safety (1 barrier/tile): between barrier t and t+1, reads hit buf[t&1], writes go
// to buf[(t+1)&1] -- disjoint. Pre-barrier lgkmcnt(0) on every wave drains both its
// ds_reads and ds_writes before it arrives, so cross-wave reuse of a buffer is ordered
// by the barrier itself.
template <int K, int NPW>
__global__ __launch_bounds__(256) void k_gemm_mfma(
    const float* __restrict__ A, const unsigned short* __restrict__ Bt_hi,
    const unsigned short* __restrict__ Bt_lo, const float* __restrict__ dinv,
    float* __restrict__ Hs, int M) {
    constexpr int N = 64 * NPW;
    constexpr int LDA = 72;       // shorts; 144 B rows: frag b128 reads land 2-way (free)
    constexpr int NT = K / 64;    // number of 64-k tiles (8 or 2 -> always even)
    static_assert((NT & 1) == 0, "NT must be even");
    __shared__ __align__(16) unsigned short As_hi[2][64 * LDA];
    __shared__ __align__(16) unsigned short As_lo[2][64 * LDA];

    const int tid = threadIdx.x;
    const int w = tid >> 6;
    const int lane = tid & 63;
    const int m = lane & 15;
    const int quad = lane >> 4;
    const int m0 = blockIdx.x * 64;

    // staging coords: thread handles rows srow+16i, fixed 4-float column skk
    const int srow = tid >> 4;
    const int skk = (tid & 15) << 2;

    floatx4 acc[4][NPW];
#pragma unroll
    for (int mi = 0; mi < 4; ++mi)
#pragma unroll
        for (int ni = 0; ni < NPW; ++ni) acc[mi][ni] = (floatx4){0.f, 0.f, 0.f, 0.f};

    float4 pfA[4], pfB[4];

    // issue loads of k-tile t0 into pf (zero-filled out of range)
    auto issue = [&](float4* pf, int t0) {
#pragma unroll
        for (int i = 0; i < 4; ++i) {
            int gm = m0 + srow + 16 * i;
            pf[i] = make_float4(0.f, 0.f, 0.f, 0.f);
            if (t0 < NT && gm < M) pf[i] = *(const float4*)&A[(long)gm * K + t0 * 64 + skk];
        }
    };
    // convert pf (split bf16) into LDS buffer b
    auto conv = [&](const float4* pf, int b) {
#pragma unroll
        for (int i = 0; i < 4; ++i) {
            ushort4 h, l;
            h.x = f2bf(pf[i].x); l.x = f2bf(pf[i].x - bf2f(h.x));
            h.y = f2bf(pf[i].y); l.y = f2bf(pf[i].y - bf2f(h.y));
            h.z = f2bf(pf[i].z); l.z = f2bf(pf[i].z - bf2f(h.z));
            h.w = f2bf(pf[i].w); l.w = f2bf(pf[i].w - bf2f(h.w));
            int off = (srow + 16 * i) * LDA + skk;
            *(ushort4*)&As_hi[b][off] = h;
            *(ushort4*)&As_lo[b][off] = l;
        }
    };
    // MFMA over LDS buffer b with B k-tile t0
    auto compute = [&](int b, int t0) {
#pragma unroll
        for (int s = 0; s < 2; ++s) {
            short8 ah[4], al[4];
#pragma unroll
            for (int mi = 0; mi < 4; ++mi) {
                int off = (mi * 16 + m) * LDA + s * 32 + quad * 8;
                ah[mi] = *(const short8*)&As_hi[b][off];
                al[mi] = *(const short8*)&As_lo[b][off];
            }
#pragma unroll
            for (int ni = 0; ni < NPW; ++ni) {
                int n = (w * NPW + ni) * 16 + m;
                long boff = (long)n * K + t0 * 64 + s * 32 + quad * 8;
                short8 bh = *(const short8*)&Bt_hi[boff];
                short8 bl = *(const short8*)&Bt_lo[boff];
#pragma unroll
                for (int mi = 0; mi < 4; ++mi) {
                    acc[mi][ni] = __builtin_amdgcn_mfma_f32_16x16x32_bf16(ah[mi], bh, acc[mi][ni], 0, 0, 0);
                    acc[mi][ni] = __builtin_amdgcn_mfma_f32_16x16x32_bf16(ah[mi], bl, acc[mi][ni], 0, 0, 0);
                    acc[mi][ni] = __builtin_amdgcn_mfma_f32_16x16x32_bf16(al[mi], bh, acc[mi][ni], 0, 0, 0);
                }
            }
        }
    };
    auto bar = [&]() {
        asm volatile("" ::: "memory");
        asm volatile("s_waitcnt lgkmcnt(0)" ::: "memory");
        __builtin_amdgcn_s_barrier();
        asm volatile("" ::: "memory");
    };

    // prologue: tiles 0 and 1 in flight; tile 0 converted into buf 0
    issue(pfA, 0);
    issue(pfB, 1);
    conv(pfA, 0);
    bar();  // buf0 ready

#pragma unroll
    for (int t = 0; t < NT; t += 2) {
        // --- even tile t: read buf0, fill buf1 with tile t+1 ---
        issue(pfA, t + 2);   // depth-2: consumed at end of tile t+1
        compute(0, t);
        conv(pfB, 1);        // tile t+1 (issued one tile ago) -> buf1
        bar();               // buf1 ready
        // --- odd tile t+1: read buf1, fill buf0 with tile t+2 ---
        issue(pfB, t + 3);
        compute(1, t + 1);
        if (t + 2 < NT) conv(pfA, 0);
        bar();               // buf0 ready
    }

    // epilogue: C/D layout col=lane&15, row=quad*4+reg; scale by dinv[row]
#pragma unroll
    for (int mi = 0; mi < 4; ++mi) {
#pragma unroll
        for (int r = 0; r < 4; ++r) {
            int row = m0 + mi * 16 + quad * 4 + r;
            if (row < M) {
                float dv = dinv[row];
#pragma unroll
                for (int ni = 0; ni < NPW; ++ni) {
                    int n = (w * NPW + ni) * 16 + m;
                    Hs[(long)row * N + n] = acc[mi][ni][r] * dv;
                }
            }
        }
    }
}

// ---------------- CSR aggregation, wave per node, 4x unrolled gathers ----------------
__global__ __launch_bounds__(256) void k_agg1(
    const float* __restrict__ h, const int* __restrict__ row_ptr,
    const int* __restrict__ col, const float* __restrict__ dinv,
    const float* __restrict__ bias, float* __restrict__ z, int n) {
    int node = blockIdx.x * 4 + (threadIdx.x >> 6);
    node = __builtin_amdgcn_readfirstlane(node);
    if (node >= n) return;
    int lane = threadIdx.x & 63;
    const float2* hp = (const float2*)h;
    float2 acc = hp[(long)node * 64 + lane];  // self-loop
    int rs = row_ptr[node], re = row_ptr[node + 1];
    int j = rs;
    for (; j + 4 <= re; j += 4) {
        int s0 = col[j], s1 = col[j + 1], s2 = col[j + 2], s3 = col[j + 3];
        float2 v0 = hp[(long)s0 * 64 + lane];
        float2 v1 = hp[(long)s1 * 64 + lane];
        float2 v2 = hp[(long)s2 * 64 + lane];
        float2 v3 = hp[(long)s3 * 64 + lane];
        acc.x += v0.x + v1.x + v2.x + v3.x;
        acc.y += v0.y + v1.y + v2.y + v3.y;
    }
    for (; j < re; ++j) {
        int s = col[j];
        float2 v = hp[(long)s * 64 + lane];
        acc.x += v.x;
        acc.y += v.y;
    }
    float dv = dinv[node];
    float2 b = ((const float2*)bias)[lane];
    acc.x = fmaxf(fmaf(acc.x, dv, b.x), 0.f);
    acc.y = fmaxf(fmaf(acc.y, dv, b.y), 0.f);
    ((float2*)z)[(long)node * 64 + lane] = acc;
}

__global__ __launch_bounds__(256) void k_agg2(
    const float* __restrict__ h, const int* __restrict__ row_ptr,
    const int* __restrict__ col, const float* __restrict__ dinv,
    const float* __restrict__ bias, float* __restrict__ z, int n) {
    int node = blockIdx.x * 4 + (threadIdx.x >> 6);
    node = __builtin_amdgcn_readfirstlane(node);
    if (node >= n) return;
    int lane = threadIdx.x & 63;
    float acc = h[(long)node * 64 + lane];  // self-loop
    int rs = row_ptr[node], re = row_ptr[node + 1];
    int j = rs;
    for (; j + 4 <= re; j += 4) {
        int s0 = col[j], s1 = col[j + 1], s2 = col[j + 2], s3 = col[j + 3];
        acc += h[(long)s0 * 64 + lane] + h[(long)s1 * 64 + lane] +
               h[(long)s2 * 64 + lane] + h[(long)s3 * 64 + lane];
    }
    for (; j < re; ++j) acc += h[(long)col[j] * 64 + lane];
    z[(long)node * 64 + lane] = fmaf(acc, dinv[node], bias[lane]);
}

// ---------------- decoder ----------------
__global__ void k_dot(const float* __restrict__ z2, const int* __restrict__ es,
                      const int* __restrict__ ed, float* __restrict__ out, int L) {
    int gid = blockIdx.x * blockDim.x + threadIdx.x;
    int wid = gid >> 6;
    int lane = threadIdx.x & 63;
    if (wid >= L) return;
    int a = es[wid], b = ed[wid];
    float v = z2[(long)a * OUT_C + lane] * z2[(long)b * OUT_C + lane];
#pragma unroll
    for (int off = 32; off > 0; off >>= 1) v += __shfl_down(v, off);
    if (lane == 0) out[wid] = v;
}

extern "C" void kernel_launch(void* const* d_in, const int* in_sizes, int n_in,
                              void* d_out, int out_size, void* d_ws, size_t ws_size,
                              hipStream_t stream) {
    const float* x = (const float*)d_in[0];
    const int* ei = (const int*)d_in[1];
    const int* eli = (const int*)d_in[2];
    const float* W1 = (const float*)d_in[3];
    const float* b1 = (const float*)d_in[4];
    const float* W2 = (const float*)d_in[5];
    const float* b2 = (const float*)d_in[6];
    float* out = (float*)d_out;

    const int N = in_sizes[0] / IN_C;  // 50000
    const int E = in_sizes[1] / 2;     // 800000
    const int L = in_sizes[2] / 2;     // 100000
    const int* src = ei;
    const int* dst = ei + E;
    const int* es = eli;
    const int* ed = eli + L;

    const int Npad = (N + 63) & ~63;
    const int Epad = (E + 3) & ~3;

    // workspace layout (~56 MB)
    int* cnt = (int*)d_ws;             // Npad
    int* cur = cnt + Npad;             // Npad
    int* row_ptr = cur + Npad;         // Npad + 64
    int* bsum = row_ptr + Npad + 64;   // 256
    int* col = bsum + 256;             // Epad
    float* dinv = (float*)(col + Epad);    // Npad
    float* h1s = dinv + Npad;              // N*128
    float* z1 = h1s + (long)N * HID_C;     // N*128
    float* h2s = h1s;                      // alias: h1s dead after agg1
    float* z2 = h1s + (long)N * OUT_C;     // alias: disjoint from h2s
    unsigned short* wt1_hi = (unsigned short*)(z1 + (long)N * HID_C);  // 512*128
    unsigned short* wt1_lo = wt1_hi + IN_C * HID_C;
    unsigned short* wt2_hi = wt1_lo + IN_C * HID_C;                    // 128*64
    unsigned short* wt2_lo = wt2_hi + HID_C * OUT_C;

    const int TPB = 256;
    const int nb = (N + 255) / 256;

    // weight prep
    k_prep_w<<<(IN_C * HID_C + TPB - 1) / TPB, TPB, 0, stream>>>(W1, wt1_hi, wt1_lo, IN_C, HID_C);
    k_prep_w<<<(HID_C * OUT_C + TPB - 1) / TPB, TPB, 0, stream>>>(W2, wt2_hi, wt2_lo, HID_C, OUT_C);

    // CSR build + dinv
    k_zero_int<<<(2 * Npad + TPB - 1) / TPB, TPB, 0, stream>>>(cnt, 2 * Npad);
    k_count<<<(E + TPB - 1) / TPB, TPB, 0, stream>>>(dst, cnt, E);
    k_dinv<<<(N + TPB - 1) / TPB, TPB, 0, stream>>>(cnt, dinv, N);
    k_blocksum<<<nb, 256, 0, stream>>>(cnt, bsum, N);
    k_scanpartials<<<1, 256, 0, stream>>>(bsum, nb);
    k_scanfinal<<<nb, 256, 0, stream>>>(cnt, bsum, row_ptr, N, E);
    k_fill<<<(E + TPB - 1) / TPB, TPB, 0, stream>>>(src, dst, row_ptr, cur, col, E);

    // layer 1  (BM=64: 782 blocks)
    k_gemm_mfma<IN_C, 2><<<(N + 63) / 64, 256, 0, stream>>>(x, wt1_hi, wt1_lo, dinv, h1s, N);
    k_agg1<<<(N + 3) / 4, 256, 0, stream>>>(h1s, row_ptr, col, dinv, b1, z1, N);

    // layer 2
    k_gemm_mfma<HID_C, 1><<<(N + 63) / 64, 256, 0, stream>>>(z1, wt2_hi, wt2_lo, dinv, h2s, N);
    k_agg2<<<(N + 3) / 4, 256, 0, stream>>>(h2s, row_ptr, col, dinv, b2, z2, N);

    // decoder
    k_dot<<<((long)L * 64 + TPB - 1) / TPB, TPB, 0, stream>>>(z2, es, ed, out, L);
}

// Round 4
// 380.139 us; speedup vs baseline: 1.1859x; 1.0866x over previous
//
#include <hip/hip_runtime.h>

// GCN 2-layer + edge dot decoder. Dims fixed: in=512, hid=128, out=64.
#define IN_C  512
#define HID_C 128
#define OUT_C 64

using short8 = __attribute__((ext_vector_type(8))) short;   // 8 bf16
using floatx4 = __attribute__((ext_vector_type(4))) float;  // mfma acc

__device__ inline unsigned short f2bf(float f) {  // RNE
    unsigned u = __builtin_bit_cast(unsigned, f);
    u += 0x7FFFu + ((u >> 16) & 1u);
    return (unsigned short)(u >> 16);
}
__device__ inline float bf2f(unsigned short h) {
    unsigned u = ((unsigned)h) << 16;
    return __builtin_bit_cast(float, u);
}
__device__ inline unsigned short f2h(float f) {  // fp32 -> fp16 RNE
    _Float16 h = (_Float16)f;
    return __builtin_bit_cast(unsigned short, h);
}
__device__ inline float h2f(unsigned v) {  // low 16 bits = fp16
    return (float)__builtin_bit_cast(_Float16, (unsigned short)v);
}

// ---------------- CSR build ----------------
__global__ void k_zero_int(int* __restrict__ p, int n) {
    int i = blockIdx.x * blockDim.x + threadIdx.x;
    if (i < n) p[i] = 0;
}

__global__ void k_count(const int* __restrict__ dst, int* __restrict__ cnt, int e) {
    int i = blockIdx.x * blockDim.x + threadIdx.x;
    if (i < e) atomicAdd(&cnt[dst[i]], 1);
}

__global__ void k_dinv(const int* __restrict__ cnt, float* __restrict__ dinv, int n) {
    int i = blockIdx.x * blockDim.x + threadIdx.x;
    if (i < n) dinv[i] = rsqrtf(1.0f + (float)cnt[i]);  // +1 self-loop
}

__global__ void k_blocksum(const int* __restrict__ cnt, int* __restrict__ bsum, int n) {
    __shared__ int sdata[256];
    int t = threadIdx.x;
    int i = blockIdx.x * 256 + t;
    sdata[t] = (i < n) ? cnt[i] : 0;
    __syncthreads();
    for (int s = 128; s > 0; s >>= 1) {
        if (t < s) sdata[t] += sdata[t + s];
        __syncthreads();
    }
    if (t == 0) bsum[blockIdx.x] = sdata[0];
}

__global__ void k_scanpartials(int* __restrict__ bsum, int nb) {
    __shared__ int sdata[256];
    int t = threadIdx.x;
    int orig = (t < nb) ? bsum[t] : 0;
    sdata[t] = orig;
    __syncthreads();
    for (int off = 1; off < 256; off <<= 1) {
        int v = (t >= off) ? sdata[t - off] : 0;
        __syncthreads();
        sdata[t] += v;
        __syncthreads();
    }
    if (t < nb) bsum[t] = sdata[t] - orig;  // exclusive
}

__global__ void k_scanfinal(const int* __restrict__ cnt, const int* __restrict__ bsum_ex,
                            int* __restrict__ row_ptr, int n, int e_total) {
    __shared__ int sdata[256];
    int t = threadIdx.x;
    int i = blockIdx.x * 256 + t;
    int orig = (i < n) ? cnt[i] : 0;
    sdata[t] = orig;
    __syncthreads();
    for (int off = 1; off < 256; off <<= 1) {
        int v = (t >= off) ? sdata[t - off] : 0;
        __syncthreads();
        sdata[t] += v;
        __syncthreads();
    }
    if (i < n) row_ptr[i] = sdata[t] - orig + bsum_ex[blockIdx.x];
    if (i == 0) row_ptr[n] = e_total;
}

__global__ void k_fill(const int* __restrict__ src, const int* __restrict__ dst,
                       const int* __restrict__ row_ptr, int* __restrict__ cur,
                       int* __restrict__ col, int e) {
    int i = blockIdx.x * blockDim.x + threadIdx.x;
    if (i < e) {
        int d = dst[i];
        int pos = atomicAdd(&cur[d], 1);
        col[row_ptr[d] + pos] = src[i];
    }
}

// ---------------- weight prep: W [K][N] fp32 -> Wt_hi/Wt_lo [N][K] bf16 ----------------
__global__ void k_prep_w(const float* __restrict__ W, unsigned short* __restrict__ hi,
                         unsigned short* __restrict__ lo, int K, int N) {
    int i = blockIdx.x * blockDim.x + threadIdx.x;
    if (i >= K * N) return;
    int k = i / N, n = i % N;
    float v = W[i];
    unsigned short h = f2bf(v);
    float r = v - bf2f(h);
    hi[(long)n * K + k] = h;
    lo[(long)n * K + k] = f2bf(r);
}

// ---------------- split-bf16 MFMA GEMM, register-prefetch double-buffered ----------------
// R0 structure (best measured). Output is fp16 (halves write traffic and, more
// importantly, halves the downstream gather traffic in the aggregation kernels).
template <int K, int NPW>
__global__ __launch_bounds__(256) void k_gemm_mfma(
    const float* __restrict__ A, const unsigned short* __restrict__ Bt_hi,
    const unsigned short* __restrict__ Bt_lo, const float* __restrict__ dinv,
    unsigned short* __restrict__ Hs, int M) {
    constexpr int N = 64 * NPW;
    constexpr int LDA = 72;       // shorts; 144 B rows: frag b128 reads land 2-way (free)
    constexpr int NT = K / 64;    // number of 64-k tiles
    __shared__ __align__(16) unsigned short As_hi[2][64 * LDA];
    __shared__ __align__(16) unsigned short As_lo[2][64 * LDA];

    const int tid = threadIdx.x;
    const int w = tid >> 6;
    const int lane = tid & 63;
    const int m = lane & 15;
    const int quad = lane >> 4;
    const int m0 = blockIdx.x * 64;

    // staging coords: thread handles rows srow+16i, fixed 4-float column skk
    const int srow = tid >> 4;
    const int skk = (tid & 15) << 2;

    floatx4 acc[4][NPW];
#pragma unroll
    for (int mi = 0; mi < 4; ++mi)
#pragma unroll
        for (int ni = 0; ni < NPW; ++ni) acc[mi][ni] = (floatx4){0.f, 0.f, 0.f, 0.f};

    float4 pf[4];
    // prologue: load + convert tile 0 into buf 0
#pragma unroll
    for (int i = 0; i < 4; ++i) {
        int gm = m0 + srow + 16 * i;
        pf[i] = make_float4(0.f, 0.f, 0.f, 0.f);
        if (gm < M) pf[i] = *(const float4*)&A[(long)gm * K + skk];
    }
#pragma unroll
    for (int i = 0; i < 4; ++i) {
        ushort4 h, l;
        h.x = f2bf(pf[i].x); l.x = f2bf(pf[i].x - bf2f(h.x));
        h.y = f2bf(pf[i].y); l.y = f2bf(pf[i].y - bf2f(h.y));
        h.z = f2bf(pf[i].z); l.z = f2bf(pf[i].z - bf2f(h.z));
        h.w = f2bf(pf[i].w); l.w = f2bf(pf[i].w - bf2f(h.w));
        int off = (srow + 16 * i) * LDA + skk;
        *(ushort4*)&As_hi[0][off] = h;
        *(ushort4*)&As_lo[0][off] = l;
    }

    for (int t = 0; t < NT; ++t) {
        __syncthreads();  // buf[t&1] fully written; prior readers of buf[(t+1)&1] done
        const int buf = t & 1;
        // prefetch next tile into registers (latency overlaps compute below)
        if (t + 1 < NT) {
#pragma unroll
            for (int i = 0; i < 4; ++i) {
                int gm = m0 + srow + 16 * i;
                pf[i] = make_float4(0.f, 0.f, 0.f, 0.f);
                if (gm < M) pf[i] = *(const float4*)&A[(long)gm * K + (t + 1) * 64 + skk];
            }
        }
        // compute from buf
#pragma unroll
        for (int s = 0; s < 2; ++s) {
            short8 ah[4], al[4];
#pragma unroll
            for (int mi = 0; mi < 4; ++mi) {
                int off = (mi * 16 + m) * LDA + s * 32 + quad * 8;
                ah[mi] = *(const short8*)&As_hi[buf][off];
                al[mi] = *(const short8*)&As_lo[buf][off];
            }
#pragma unroll
            for (int ni = 0; ni < NPW; ++ni) {
                int n = (w * NPW + ni) * 16 + m;
                long boff = (long)n * K + t * 64 + s * 32 + quad * 8;
                short8 bh = *(const short8*)&Bt_hi[boff];
                short8 bl = *(const short8*)&Bt_lo[boff];
#pragma unroll
                for (int mi = 0; mi < 4; ++mi) {
                    acc[mi][ni] = __builtin_amdgcn_mfma_f32_16x16x32_bf16(ah[mi], bh, acc[mi][ni], 0, 0, 0);
                    acc[mi][ni] = __builtin_amdgcn_mfma_f32_16x16x32_bf16(ah[mi], bl, acc[mi][ni], 0, 0, 0);
                    acc[mi][ni] = __builtin_amdgcn_mfma_f32_16x16x32_bf16(al[mi], bh, acc[mi][ni], 0, 0, 0);
                }
            }
        }
        // convert prefetched regs into the other buffer
        if (t + 1 < NT) {
#pragma unroll
            for (int i = 0; i < 4; ++i) {
                ushort4 h, l;
                h.x = f2bf(pf[i].x); l.x = f2bf(pf[i].x - bf2f(h.x));
                h.y = f2bf(pf[i].y); l.y = f2bf(pf[i].y - bf2f(h.y));
                h.z = f2bf(pf[i].z); l.z = f2bf(pf[i].z - bf2f(h.z));
                h.w = f2bf(pf[i].w); l.w = f2bf(pf[i].w - bf2f(h.w));
                int off = (srow + 16 * i) * LDA + skk;
                *(ushort4*)&As_hi[buf ^ 1][off] = h;
                *(ushort4*)&As_lo[buf ^ 1][off] = l;
            }
        }
    }

    // epilogue: C/D layout col=lane&15, row=quad*4+reg; scale by dinv[row]; fp16 store
#pragma unroll
    for (int mi = 0; mi < 4; ++mi) {
#pragma unroll
        for (int r = 0; r < 4; ++r) {
            int row = m0 + mi * 16 + quad * 4 + r;
            if (row < M) {
                float dv = dinv[row];
#pragma unroll
                for (int ni = 0; ni < NPW; ++ni) {
                    int n = (w * NPW + ni) * 16 + m;
                    Hs[(long)row * N + n] = f2h(acc[mi][ni][r] * dv);
                }
            }
        }
    }
}

// ---------------- CSR aggregation, wave per node, half-wave edge pairing ----------------
// h is fp16 (halved gather traffic). Lanes 0-31 process even edges, 32-63 odd edges
// (uniform trip count -> no divergence); halves combined via __shfl at the end.
// agg1: 128 ch -> 8 B/lane per gather (uint2 = 4 fp16). Accum fp32, z1 out fp32 + relu.
__global__ __launch_bounds__(256) void k_agg1(
    const unsigned short* __restrict__ h, const int* __restrict__ row_ptr,
    const int* __restrict__ col, const float* __restrict__ dinv,
    const float* __restrict__ bias, float* __restrict__ z, int n) {
    int node = blockIdx.x * 4 + (threadIdx.x >> 6);
    node = __builtin_amdgcn_readfirstlane(node);
    if (node >= n) return;
    int lane = threadIdx.x & 63;
    int half = lane >> 5, li = lane & 31;
    const uint2* hp = (const uint2*)h;  // 32 uint2 per row (128 ch fp16)
    float4 acc = make_float4(0.f, 0.f, 0.f, 0.f);
    if (half == 0) {  // self-loop counted once
        uint2 v = hp[(long)node * 32 + li];
        acc.x = h2f(v.x); acc.y = h2f(v.x >> 16);
        acc.z = h2f(v.y); acc.w = h2f(v.y >> 16);
    }
    int rs = row_ptr[node], re = row_ptr[node + 1];
    int cnt = re - rs, pairs = cnt >> 1;
    int j = rs + half;
    int p = 0;
    for (; p + 4 <= pairs; p += 4, j += 8) {
        int s0 = col[j], s1 = col[j + 2], s2 = col[j + 4], s3 = col[j + 6];
        uint2 v0 = hp[(long)s0 * 32 + li];
        uint2 v1 = hp[(long)s1 * 32 + li];
        uint2 v2 = hp[(long)s2 * 32 + li];
        uint2 v3 = hp[(long)s3 * 32 + li];
        acc.x += h2f(v0.x) + h2f(v1.x) + h2f(v2.x) + h2f(v3.x);
        acc.y += h2f(v0.x >> 16) + h2f(v1.x >> 16) + h2f(v2.x >> 16) + h2f(v3.x >> 16);
        acc.z += h2f(v0.y) + h2f(v1.y) + h2f(v2.y) + h2f(v3.y);
        acc.w += h2f(v0.y >> 16) + h2f(v1.y >> 16) + h2f(v2.y >> 16) + h2f(v3.y >> 16);
    }
    for (; p < pairs; ++p, j += 2) {
        int s = col[j];
        uint2 v = hp[(long)s * 32 + li];
        acc.x += h2f(v.x); acc.y += h2f(v.x >> 16);
        acc.z += h2f(v.y); acc.w += h2f(v.y >> 16);
    }
    if ((cnt & 1) && half == 0) {  // odd tail handled by low half
        int s = col[re - 1];
        uint2 v = hp[(long)s * 32 + li];
        acc.x += h2f(v.x); acc.y += h2f(v.x >> 16);
        acc.z += h2f(v.y); acc.w += h2f(v.y >> 16);
    }
    // combine halves
    float ox = __shfl(acc.x, li + 32);
    float oy = __shfl(acc.y, li + 32);
    float oz = __shfl(acc.z, li + 32);
    float ow = __shfl(acc.w, li + 32);
    if (half == 0) {
        acc.x += ox; acc.y += oy; acc.z += oz; acc.w += ow;
        float dv = dinv[node];
        float4 b = ((const float4*)bias)[li];
        float4 o;
        o.x = fmaxf(fmaf(acc.x, dv, b.x), 0.f);
        o.y = fmaxf(fmaf(acc.y, dv, b.y), 0.f);
        o.z = fmaxf(fmaf(acc.z, dv, b.z), 0.f);
        o.w = fmaxf(fmaf(acc.w, dv, b.w), 0.f);
        ((float4*)z)[(long)node * 32 + li] = o;
    }
}

// agg2: 64 ch -> 4 B/lane per gather (uint = 2 fp16). z2 out fp32 (no relu).
__global__ __launch_bounds__(256) void k_agg2(
    const unsigned short* __restrict__ h, const int* __restrict__ row_ptr,
    const int* __restrict__ col, const float* __restrict__ dinv,
    const float* __restrict__ bias, float* __restrict__ z, int n) {
    int node = blockIdx.x * 4 + (threadIdx.x >> 6);
    node = __builtin_amdgcn_readfirstlane(node);
    if (node >= n) return;
    int lane = threadIdx.x & 63;
    int half = lane >> 5, li = lane & 31;
    const unsigned* hp = (const unsigned*)h;  // 32 uints per row (64 ch fp16)
    float2 acc = make_float2(0.f, 0.f);
    if (half == 0) {  // self-loop
        unsigned v = hp[(long)node * 32 + li];
        acc.x = h2f(v); acc.y = h2f(v >> 16);
    }
    int rs = row_ptr[node], re = row_ptr[node + 1];
    int cnt = re - rs, pairs = cnt >> 1;
    int j = rs + half;
    int p = 0;
    for (; p + 4 <= pairs; p += 4, j += 8) {
        int s0 = col[j], s1 = col[j + 2], s2 = col[j + 4], s3 = col[j + 6];
        unsigned v0 = hp[(long)s0 * 32 + li];
        unsigned v1 = hp[(long)s1 * 32 + li];
        unsigned v2 = hp[(long)s2 * 32 + li];
        unsigned v3 = hp[(long)s3 * 32 + li];
        acc.x += h2f(v0) + h2f(v1) + h2f(v2) + h2f(v3);
        acc.y += h2f(v0 >> 16) + h2f(v1 >> 16) + h2f(v2 >> 16) + h2f(v3 >> 16);
    }
    for (; p < pairs; ++p, j += 2) {
        unsigned v = hp[(long)col[j] * 32 + li];
        acc.x += h2f(v); acc.y += h2f(v >> 16);
    }
    if ((cnt & 1) && half == 0) {
        unsigned v = hp[(long)col[re - 1] * 32 + li];
        acc.x += h2f(v); acc.y += h2f(v >> 16);
    }
    float ox = __shfl(acc.x, li + 32);
    float oy = __shfl(acc.y, li + 32);
    if (half == 0) {
        acc.x += ox; acc.y += oy;
        float dv = dinv[node];
        float2 b = ((const float2*)bias)[li];
        float2 o;
        o.x = fmaf(acc.x, dv, b.x);
        o.y = fmaf(acc.y, dv, b.y);
        ((float2*)z)[(long)node * 32 + li] = o;
    }
}

// ---------------- decoder ----------------
__global__ void k_dot(const float* __restrict__ z2, const int* __restrict__ es,
                      const int* __restrict__ ed, float* __restrict__ out, int L) {
    int gid = blockIdx.x * blockDim.x + threadIdx.x;
    int wid = gid >> 6;
    int lane = threadIdx.x & 63;
    if (wid >= L) return;
    int a = es[wid], b = ed[wid];
    float v = z2[(long)a * OUT_C + lane] * z2[(long)b * OUT_C + lane];
#pragma unroll
    for (int off = 32; off > 0; off >>= 1) v += __shfl_down(v, off);
    if (lane == 0) out[wid] = v;
}

extern "C" void kernel_launch(void* const* d_in, const int* in_sizes, int n_in,
                              void* d_out, int out_size, void* d_ws, size_t ws_size,
                              hipStream_t stream) {
    const float* x = (const float*)d_in[0];
    const int* ei = (const int*)d_in[1];
    const int* eli = (const int*)d_in[2];
    const float* W1 = (const float*)d_in[3];
    const float* b1 = (const float*)d_in[4];
    const float* W2 = (const float*)d_in[5];
    const float* b2 = (const float*)d_in[6];
    float* out = (float*)d_out;

    const int N = in_sizes[0] / IN_C;  // 50000
    const int E = in_sizes[1] / 2;     // 800000
    const int L = in_sizes[2] / 2;     // 100000
    const int* src = ei;
    const int* dst = ei + E;
    const int* es = eli;
    const int* ed = eli + L;

    const int Npad = (N + 63) & ~63;
    const int Epad = (E + 3) & ~3;

    // workspace layout (~56 MB)
    int* cnt = (int*)d_ws;             // Npad
    int* cur = cnt + Npad;             // Npad
    int* row_ptr = cur + Npad;         // Npad + 64
    int* bsum = row_ptr + Npad + 64;   // 256
    int* col = bsum + 256;             // Epad
    float* dinv = (float*)(col + Epad);                   // Npad
    unsigned short* h1s = (unsigned short*)(dinv + Npad); // N*128 fp16 (16B-aligned)
    float* z1 = (float*)(h1s + (long)N * HID_C);          // N*128 fp32
    unsigned short* h2s = h1s;                            // alias: h1s dead after agg1
    float* z2 = z1 + (long)N * HID_C;                     // N*64 fp32
    unsigned short* wt1_hi = (unsigned short*)(z2 + (long)N * OUT_C);  // 512*128
    unsigned short* wt1_lo = wt1_hi + IN_C * HID_C;
    unsigned short* wt2_hi = wt1_lo + IN_C * HID_C;                    // 128*64
    unsigned short* wt2_lo = wt2_hi + HID_C * OUT_C;

    const int TPB = 256;
    const int nb = (N + 255) / 256;

    // weight prep
    k_prep_w<<<(IN_C * HID_C + TPB - 1) / TPB, TPB, 0, stream>>>(W1, wt1_hi, wt1_lo, IN_C, HID_C);
    k_prep_w<<<(HID_C * OUT_C + TPB - 1) / TPB, TPB, 0, stream>>>(W2, wt2_hi, wt2_lo, HID_C, OUT_C);

    // CSR build + dinv
    k_zero_int<<<(2 * Npad + TPB - 1) / TPB, TPB, 0, stream>>>(cnt, 2 * Npad);
    k_count<<<(E + TPB - 1) / TPB, TPB, 0, stream>>>(dst, cnt, E);
    k_dinv<<<(N + TPB - 1) / TPB, TPB, 0, stream>>>(cnt, dinv, N);
    k_blocksum<<<nb, 256, 0, stream>>>(cnt, bsum, N);
    k_scanpartials<<<1, 256, 0, stream>>>(bsum, nb);
    k_scanfinal<<<nb, 256, 0, stream>>>(cnt, bsum, row_ptr, N, E);
    k_fill<<<(E + TPB - 1) / TPB, TPB, 0, stream>>>(src, dst, row_ptr, cur, col, E);

    // layer 1
    k_gemm_mfma<IN_C, 2><<<(N + 63) / 64, 256, 0, stream>>>(x, wt1_hi, wt1_lo, dinv, h1s, N);
    k_agg1<<<(N + 3) / 4, 256, 0, stream>>>(h1s, row_ptr, col, dinv, b1, z1, N);

    // layer 2
    k_gemm_mfma<HID_C, 1><<<(N + 63) / 64, 256, 0, stream>>>(z1, wt2_hi, wt2_lo, dinv, h2s, N);
    k_agg2<<<(N + 3) / 4, 256, 0, stream>>>(h2s, row_ptr, col, dinv, b2, z2, N);

    // decoder
    k_dot<<<((long)L * 64 + TPB - 1) / TPB, TPB, 0, stream>>>(z2, es, ed, out, L);
}